// Round 1
// 1096.882 us; speedup vs baseline: 1.0387x; 1.0387x over previous
//
#include <hip/hip_runtime.h>

#define B_    1024
#define S_    50
#define L_    20
#define NOUT  100001

typedef __attribute__((ext_vector_type(8))) short bh8;   // 8 bf16 (4 VGPRs)
typedef __attribute__((ext_vector_type(4))) float fx4;   // MFMA C/D

__device__ __forceinline__ unsigned short f2bf(float x){
  unsigned u = __float_as_uint(x);
  unsigned r = (u + 0x7FFFu + ((u >> 16) & 1u)) >> 16;   // RNE
  return (unsigned short)r;
}
__device__ __forceinline__ float bf2f(unsigned short h){
  return __uint_as_float(((unsigned)h) << 16);
}
__device__ __forceinline__ float sigm(float x){
  return __builtin_amdgcn_rcpf(1.f + __expf(-x));
}
__device__ __forceinline__ float tanh_(float x){
  return 1.f - 2.f*__builtin_amdgcn_rcpf(__expf(2.f*x) + 1.f);
}

// split x into bf16 hi + bf16 lo (hi+lo == x to ~2^-17 rel)
__device__ __forceinline__ void frag_convert_row(const float* src, bh8& hv, bh8& lv){
  #pragma unroll
  for (int j = 0; j < 8; j++){
    float x = src[j];
    unsigned short hb = f2bf(x);
    hv[j] = (short)hb;
    lv[j] = (short)f2bf(x - bf2f(hb));
  }
}

// ---------------------------------------------------------------------------
// LSTM weight prep: single bf16 plane in per-lane B-fragment order.
// Layout: [layer(2)][nt(32)][kt(8)][lane(64)][8 bf16]
// B-frag (16x16x32): n = nt*16 + (lane&15), k = kt*32 + (lane>>4)*8 + j.
// K=256 = [x(128) | h(128)] -> W_ih cols then W_hh cols. bias = b_ih + b_hh.
__global__ __launch_bounds__(256) void prep_lstm_w(
    const float* __restrict__ Wih0, const float* __restrict__ Whh0,
    const float* __restrict__ bih0, const float* __restrict__ bhh0,
    const float* __restrict__ Wih1, const float* __restrict__ Whh1,
    const float* __restrict__ bih1, const float* __restrict__ bhh1,
    short* __restrict__ wsw, float* __restrict__ wsbias){
  int tid = blockIdx.x*256 + threadIdx.x;       // 32768 total
  if (tid < 1024){
    int l = tid >> 9, n = tid & 511;
    wsbias[l*512 + n] = l ? (bih1[n] + bhh1[n]) : (bih0[n] + bhh0[n]);
  }
  if (tid >= 32768) return;
  int lane = tid & 63;
  int kt   = (tid >> 6) & 7;
  int nt   = (tid >> 9) & 31;
  int l    = tid >> 14;
  const float* Wih = l ? Wih1 : Wih0;
  const float* Whh = l ? Whh1 : Whh0;
  int n = nt*16 + (lane & 15);
  int kbase = kt*32 + (lane >> 4)*8;
  size_t base = ((((size_t)l*32 + nt)*8 + kt)*64 + lane)*8;
  for (int j = 0; j < 8; j++){
    int k = kbase + j;
    float w = (k < 128) ? Wih[n*128 + k] : Whh[n*128 + (k - 128)];
    wsw[base + j] = (short)f2bf(w);
  }
}

// W2 -> bf16, padded to 100016 rows (zeros).
__global__ __launch_bounds__(256) void prep_w2(const float* __restrict__ W2,
                                               short* __restrict__ out){
  long i = (long)blockIdx.x*256 + threadIdx.x;  // 100016*64 = 6,401,024
  if (i >= 100016L*64) return;
  long row = i >> 6;
  float v = (row < NOUT) ? W2[i] : 0.f;
  out[i] = (short)f2bf(v);
}

// ---------------------------------------------------------------------------
// Features -> x in A-fragment order, bf16 hi/lo planes.
// xfrag layout: [s(50)][bt(64)][plane(2)][kt(4)][lane(64)][8 bf16]
// Block = (bt, s): 16 batch rows x 128 features.
__global__ __launch_bounds__(256) void features(
    const int* __restrict__ pidx, const int* __restrict__ cidx,
    const float* __restrict__ age, const float* __restrict__ ts,
    const float* __restrict__ gender,
    const float* __restrict__ embp, const float* __restrict__ embc,
    const float* __restrict__ Wts, const float* __restrict__ bts,
    const float* __restrict__ Wuf, const float* __restrict__ bufv,
    short* __restrict__ xfrag){
  const int bx = blockIdx.x;
  const int bt = bx & 63, s = bx >> 6;
  const int b0 = bt*16;
  const int tid = threadIdx.x;
  __shared__ int pi[320], ci[320];
  __shared__ __align__(16) float XF[16][132];
  for (int i = tid; i < 640; i += 256){
    if (i < 320){
      int row = i/20, l = i - row*20;
      pi[i] = pidx[((size_t)(b0+row)*S_ + s)*L_ + l];
    } else {
      int j = i - 320;
      int row = j/20, l = j - row*20;
      ci[j] = cidx[((size_t)(b0+row)*S_ + s)*L_ + l];
    }
  }
  __syncthreads();
  const int m = tid >> 4, fg = tid & 15;
  float a[8];
  if (fg < 8){
    int f0 = fg*8;
    float4 s0 = {0,0,0,0}, s1 = {0,0,0,0};
    for (int l = 0; l < L_; l++){
      const float4* p = (const float4*)(embp + (size_t)pi[m*20+l]*64 + f0);
      float4 u = p[0], v = p[1];
      s0.x += u.x; s0.y += u.y; s0.z += u.z; s0.w += u.w;
      s1.x += v.x; s1.y += v.y; s1.z += v.z; s1.w += v.w;
    }
    a[0]=s0.x*0.05f; a[1]=s0.y*0.05f; a[2]=s0.z*0.05f; a[3]=s0.w*0.05f;
    a[4]=s1.x*0.05f; a[5]=s1.y*0.05f; a[6]=s1.z*0.05f; a[7]=s1.w*0.05f;
  } else if (fg < 12){
    int f0 = (fg-8)*8;
    float4 s0 = {0,0,0,0}, s1 = {0,0,0,0};
    for (int l = 0; l < L_; l++){
      const float4* p = (const float4*)(embc + (size_t)ci[m*20+l]*32 + f0);
      float4 u = p[0], v = p[1];
      s0.x += u.x; s0.y += u.y; s0.z += u.z; s0.w += u.w;
      s1.x += v.x; s1.y += v.y; s1.z += v.z; s1.w += v.w;
    }
    a[0]=s0.x*0.05f; a[1]=s0.y*0.05f; a[2]=s0.z*0.05f; a[3]=s0.w*0.05f;
    a[4]=s1.x*0.05f; a[5]=s1.y*0.05f; a[6]=s1.z*0.05f; a[7]=s1.w*0.05f;
  } else if (fg < 14){
    int j0 = (fg-12)*8;
    float tv = ts[(size_t)(b0+m)*S_ + s];
    #pragma unroll
    for (int e = 0; e < 8; e++) a[e] = tv*Wts[j0+e] + bts[j0+e];
  } else {
    int j0 = (fg-14)*8;
    float av = age[b0+m], gv = gender[b0+m];
    #pragma unroll
    for (int e = 0; e < 8; e++){
      int j = j0+e;
      a[e] = av*Wuf[2*j] + gv*Wuf[2*j+1] + bufv[j];
    }
  }
  {
    int f0 = fg*8;
    *(float4*)&XF[m][f0]   = (float4){a[0],a[1],a[2],a[3]};
    *(float4*)&XF[m][f0+4] = (float4){a[4],a[5],a[6],a[7]};
  }
  __syncthreads();
  // phase 2: emit fragment-order hi/lo planes
  const int kt = tid >> 6, ls = tid & 63;
  const int mm = ls & 15, a2 = ls >> 4;
  bh8 hv, lv;
  frag_convert_row(&XF[mm][kt*32 + a2*8], hv, lv);
  size_t ob = ((((size_t)s*64 + bt)*2 + 0)*4 + kt)*512 + (size_t)ls*8;
  *(bh8*)(xfrag + ob)        = hv;   // plane 0 (hi)
  *(bh8*)(xfrag + ob + 2048) = lv;   // plane 1 (lo)
}

// ---------------------------------------------------------------------------
// 2-layer LSTM, layer-pipelined wave teams. 64 blocks x 512 thr (8 waves).
// Waves 0-3 (team0): layer0 at step i.  Waves 4-7 (team1): layer1 at step i-1.
// Team-wave u owns nt = g*8 + 2u + ss (ss=0,1): j-slice [u*32, u*32+32) for all
// 4 gates -> c-state and nonlinearity fully register-local, AND the C-layout
// output columns are exactly A-frag slice kt4 = u -> the f32->bf16-hi/lo
// fragment conversion is WAVE-INTERNAL (through a per-layer LDS f32 scratch,
// ordered by lgkmcnt, no barrier). All cross-wave buffers (XA, H0, H1 frags)
// are parity double-buffered -> ONE __syncthreads() per time step (was 4).
__global__ __launch_bounds__(512, 2) void lstm_kernel(
    const short* __restrict__ xfrag, const short* __restrict__ wsw,
    const float* __restrict__ wsbias,
    const float* __restrict__ W1, const float* __restrict__ b1,
    short* __restrict__ hidden_bf){
  __shared__ __align__(16) short XAhi[2][2048], XAlo[2][2048]; // x(t) frags
  __shared__ __align__(16) short H0hi[2][2048], H0lo[2][2048]; // h0(t) frags
  __shared__ __align__(16) short H1hi[2][2048], H1lo[2][2048]; // h1(t) frags
  __shared__ __align__(16) float XH0f[16][132], XH1f[16][132]; // f32 C-tiles
  const int tid  = threadIdx.x;
  const int w    = tid >> 6, lane = tid & 63;
  const int col  = lane & 15, quad = lane >> 4;
  const int bt   = blockIdx.x;
  const int u    = w & 3;                 // team-wave index
  const bool t1  = (w >= 4);              // team1 = layer 1
  const int lsel = t1 ? 1 : 0;
  const int plane = tid >> 8, sl = tid & 255;
  const bh8* wp = (const bh8*)wsw;

  for (int idx = tid; idx < 2048; idx += 512){
    H0hi[1][idx] = 0; H0lo[1][idx] = 0;   // h0(-1)
    H1hi[0][idx] = 0; H1lo[0][idx] = 0;   // h1(-1)
  }
  float bz[2][4];
  #pragma unroll
  for (int ss = 0; ss < 2; ss++)
    #pragma unroll
    for (int g = 0; g < 4; g++)
      bz[ss][g] = wsbias[lsel*512 + (g*8 + 2*u + ss)*16 + col];
  float cst[2][4] = {{0,0,0,0},{0,0,0,0}};
  // stage x(0) into XA[0]
  {
    float4 v = *(const float4*)(xfrag + ((size_t)bt*2 + plane)*2048 + (size_t)sl*8);
    *(float4*)((plane ? XAlo[0] : XAhi[0]) + sl*8) = v;
  }
  __syncthreads();

  for (int i = 0; i <= S_; i++){
    const int cb = i & 1, pb = cb ^ 1;
    // prefetch x(i+1) (latency hidden under the MFMA phase)
    int tp = (i+1 < S_) ? i+1 : S_-1;
    float4 pf = *(const float4*)(xfrag + (((size_t)tp*64 + bt)*2 + plane)*2048 + (size_t)sl*8);

    const bool act = t1 ? (i >= 1) : (i < S_);
    if (act){
      fx4 acc[2][4];
      #pragma unroll
      for (int ss = 0; ss < 2; ss++)
        #pragma unroll
        for (int g = 0; g < 4; g++)
          acc[ss][g] = (fx4){bz[ss][g], bz[ss][g], bz[ss][g], bz[ss][g]};
      #pragma unroll
      for (int kt = 0; kt < 8; kt++){
        const short* ph;
        const short* pl;
        if (!t1){ // layer0: K = [x(i) | h0(i-1)]
          ph = (kt < 4) ? &XAhi[cb][kt*512 + lane*8] : &H0hi[pb][(kt-4)*512 + lane*8];
          pl = (kt < 4) ? &XAlo[cb][kt*512 + lane*8] : &H0lo[pb][(kt-4)*512 + lane*8];
        } else {  // layer1: K = [h0(i-1) | h1(i-2)]
          ph = (kt < 4) ? &H0hi[pb][kt*512 + lane*8] : &H1hi[pb][(kt-4)*512 + lane*8];
          pl = (kt < 4) ? &H0lo[pb][kt*512 + lane*8] : &H1lo[pb][(kt-4)*512 + lane*8];
        }
        bh8 ah = *(const bh8*)ph;
        bh8 al = *(const bh8*)pl;
        #pragma unroll
        for (int ss = 0; ss < 2; ss++)
          #pragma unroll
          for (int g = 0; g < 4; g++){
            bh8 bb = wp[(size_t)((lsel*32 + g*8 + 2*u + ss)*8 + kt)*64 + lane];
            acc[ss][g] = __builtin_amdgcn_mfma_f32_16x16x32_bf16(ah, bb, acc[ss][g], 0, 0, 0);
            acc[ss][g] = __builtin_amdgcn_mfma_f32_16x16x32_bf16(al, bb, acc[ss][g], 0, 0, 0);
          }
      }
      float (*XH)[132] = t1 ? XH1f : XH0f;
      #pragma unroll
      for (int ss = 0; ss < 2; ss++)
        #pragma unroll
        for (int r = 0; r < 4; r++){
          float cc = sigm(acc[ss][1][r])*cst[ss][r] + sigm(acc[ss][0][r])*tanh_(acc[ss][2][r]);
          cst[ss][r] = cc;
          XH[quad*4 + r][u*32 + ss*16 + col] = sigm(acc[ss][3][r])*tanh_(cc);
        }
      // wave-local convert: wave u transposes its own cols [u*32,u*32+32)
      // into A-frag slice kt4 = u (hi/lo planes). No barrier needed before
      // the read: same-wave LDS dependency (lgkmcnt-ordered).
      {
        const int mm = lane & 15, a2 = lane >> 4;
        bh8 hv, lv;
        frag_convert_row(&XH[mm][u*32 + a2*8], hv, lv);
        if (!t1){
          *(bh8*)&H0hi[cb][u*512 + lane*8] = hv;
          *(bh8*)&H0lo[cb][u*512 + lane*8] = lv;
        } else {
          *(bh8*)&H1hi[cb][u*512 + lane*8] = hv;
          *(bh8*)&H1lo[cb][u*512 + lane*8] = lv;
        }
      }
    }
    // park x(i+1) into the other parity buffer (disjoint from this iter's reads)
    *(float4*)((plane ? XAlo[pb] : XAhi[pb]) + sl*8) = pf;
    __syncthreads();   // publish H0[cb], H1[cb], XA[pb] for iter i+1
  }
  // XH1f holds h1(t=49) (written by team1 at iter 50, barrier'd). Fused head1.
  #pragma unroll
  for (int e = 0; e < 2; e++){
    int mm2 = (tid >> 6)*2 + e;
    int cc2 = tid & 63;
    float s = b1[cc2];
    #pragma unroll 8
    for (int k = 0; k < 128; k++) s += XH1f[mm2][k]*W1[cc2*128 + k];
    s = fmaxf(s, 0.f);
    hidden_bf[(size_t)(bt*16 + mm2)*64 + cc2] = (short)f2bf(s);
  }
}

// ---------------------------------------------------------------------------
// logits = hidden @ W2^T + b2. Block = (chunk of 32 n-tiles) x (one m-tile);
// results re-staged through LDS so global stores are 512B-contiguous rows.
__global__ __launch_bounds__(256) void head2(
    const short* __restrict__ hid, const short* __restrict__ w2,
    const float* __restrict__ b2, float* __restrict__ out){
  __shared__ __align__(16) float HS[4][16][132];
  const int tid = threadIdx.x;
  const int w = tid >> 6, lane = tid & 63;
  const int col = lane & 15, quad = lane >> 4;
  const int mt = blockIdx.x & 63;
  const int chunk = blockIdx.x >> 6;       // 196 chunks
  const bh8* hp = (const bh8*)hid;
  bh8 a0 = hp[(size_t)(mt*16 + col)*8 + quad];
  bh8 a1 = hp[(size_t)(mt*16 + col)*8 + 4 + quad];
  const bh8* wpt = (const bh8*)w2;
  #pragma unroll
  for (int i = 0; i < 8; i++){
    int nt = chunk*32 + w*8 + i;
    if (nt < 6251){
      int n = nt*16 + col;
      bh8 b0v = wpt[(size_t)n*8 + quad];
      bh8 b1v = wpt[(size_t)n*8 + 4 + quad];
      fx4 a = {0.f,0.f,0.f,0.f};
      a = __builtin_amdgcn_mfma_f32_16x16x32_bf16(a0, b0v, a, 0, 0, 0);
      a = __builtin_amdgcn_mfma_f32_16x16x32_bf16(a1, b1v, a, 0, 0, 0);
      float bias = (n < NOUT) ? b2[n] : 0.f;
      #pragma unroll
      for (int r = 0; r < 4; r++) HS[w][quad*4 + r][i*16 + col] = a[r] + bias;
    }
  }
  __syncthreads();
  const long rowbase = (long)mt*16;
  const int n0 = chunk*512 + w*128;
  #pragma unroll
  for (int p = 0; p < 8; p++){
    int row = p*2 + (lane >> 5);
    int c4 = (lane & 31)*4;
    int gc = n0 + c4;
    float4 v = *(const float4*)&HS[w][row][c4];
    if (gc + 3 < NOUT){
      *(float4*)&out[(rowbase + row)*NOUT + gc] = v;
    } else {
      float vv[4] = {v.x, v.y, v.z, v.w};
      #pragma unroll
      for (int k2 = 0; k2 < 4; k2++)
        if (gc + k2 < NOUT) out[(rowbase + row)*NOUT + gc + k2] = vv[k2];
    }
  }
}

// ---------------------------------------------------------------------------
extern "C" void kernel_launch(void* const* d_in, const int* in_sizes, int n_in,
                              void* d_out, int out_size, void* d_ws, size_t ws_size,
                              hipStream_t stream){
  const int*   prod = (const int*)  d_in[0];
  const int*   cat  = (const int*)  d_in[1];
  const float* age  = (const float*)d_in[2];
  const float* ts   = (const float*)d_in[3];
  const float* gen  = (const float*)d_in[4];
  const float* embp = (const float*)d_in[5];
  const float* embc = (const float*)d_in[6];
  const float* Wts  = (const float*)d_in[7];
  const float* bts  = (const float*)d_in[8];
  const float* Wuf  = (const float*)d_in[9];
  const float* bufv = (const float*)d_in[10];
  const float* Wih0 = (const float*)d_in[11];
  const float* Whh0 = (const float*)d_in[12];
  const float* bih0 = (const float*)d_in[13];
  const float* bhh0 = (const float*)d_in[14];
  const float* Wih1 = (const float*)d_in[15];
  const float* Whh1 = (const float*)d_in[16];
  const float* bih1 = (const float*)d_in[17];
  const float* bhh1 = (const float*)d_in[18];
  const float* W1   = (const float*)d_in[19];
  const float* b1   = (const float*)d_in[20];
  const float* W2   = (const float*)d_in[21];
  const float* b2   = (const float*)d_in[22];
  float* out = (float*)d_out;

  char* ws = (char*)d_ws;
  short* ws_x    = (short*)(ws);               // xfrag: 26,214,400 B
  short* ws_w    = (short*)(ws + 26214400);    // lstm W frags: 524,288 B
  float* ws_bias = (float*)(ws + 26738688);    // [2][512] f32: 4,096 B
  short* ws_hid  = (short*)(ws + 26742784);    // hidden bf16 [1024][64]: 131,072 B
  short* ws_w2   = (short*)(ws + 26873856);    // W2 bf16 [100016][64]: 12,802,048 B

  prep_lstm_w<<<128, 256, 0, stream>>>(Wih0, Whh0, bih0, bhh0,
                                       Wih1, Whh1, bih1, bhh1, ws_w, ws_bias);
  prep_w2<<<25004, 256, 0, stream>>>(W2, ws_w2);
  features<<<3200, 256, 0, stream>>>(prod, cat, age, ts, gen, embp, embc,
                                     Wts, bts, Wuf, bufv, ws_x);
  lstm_kernel<<<64, 512, 0, stream>>>(ws_x, ws_w, ws_bias, W1, b1, ws_hid);
  head2<<<196*64, 256, 0, stream>>>(ws_hid, ws_w2, b2, out);
}

// Round 2
// 983.497 us; speedup vs baseline: 1.1585x; 1.1153x over previous
//
#include <hip/hip_runtime.h>

#define B_    1024
#define S_    50
#define L_    20
#define NOUT  100001

typedef __attribute__((ext_vector_type(8))) short bh8;   // 8 bf16 (4 VGPRs)
typedef __attribute__((ext_vector_type(4))) float fx4;   // MFMA C/D

__device__ __forceinline__ unsigned short f2bf(float x){
  unsigned u = __float_as_uint(x);
  unsigned r = (u + 0x7FFFu + ((u >> 16) & 1u)) >> 16;   // RNE
  return (unsigned short)r;
}
__device__ __forceinline__ float bf2f(unsigned short h){
  return __uint_as_float(((unsigned)h) << 16);
}
__device__ __forceinline__ float sigm(float x){
  return __builtin_amdgcn_rcpf(1.f + __expf(-x));
}
__device__ __forceinline__ float tanh_(float x){
  return 1.f - 2.f*__builtin_amdgcn_rcpf(__expf(2.f*x) + 1.f);
}

// split x into bf16 hi + bf16 lo (hi+lo == x to ~2^-17 rel)
__device__ __forceinline__ void frag_convert_row(const float* src, bh8& hv, bh8& lv){
  #pragma unroll
  for (int j = 0; j < 8; j++){
    float x = src[j];
    unsigned short hb = f2bf(x);
    hv[j] = (short)hb;
    lv[j] = (short)f2bf(x - bf2f(hb));
  }
}

// ---------------------------------------------------------------------------
// LSTM weight prep: single bf16 plane in per-lane B-fragment order.
// Layout: [layer(2)][nt(32)][kt(8)][lane(64)][8 bf16]
// B-frag (16x16x32): n = nt*16 + (lane&15), k = kt*32 + (lane>>4)*8 + j.
// K=256 = [x(128) | h(128)] -> W_ih cols then W_hh cols. bias = b_ih + b_hh.
__global__ __launch_bounds__(256) void prep_lstm_w(
    const float* __restrict__ Wih0, const float* __restrict__ Whh0,
    const float* __restrict__ bih0, const float* __restrict__ bhh0,
    const float* __restrict__ Wih1, const float* __restrict__ Whh1,
    const float* __restrict__ bih1, const float* __restrict__ bhh1,
    short* __restrict__ wsw, float* __restrict__ wsbias){
  int tid = blockIdx.x*256 + threadIdx.x;       // 32768 total
  if (tid < 1024){
    int l = tid >> 9, n = tid & 511;
    wsbias[l*512 + n] = l ? (bih1[n] + bhh1[n]) : (bih0[n] + bhh0[n]);
  }
  if (tid >= 32768) return;
  int lane = tid & 63;
  int kt   = (tid >> 6) & 7;
  int nt   = (tid >> 9) & 31;
  int l    = tid >> 14;
  const float* Wih = l ? Wih1 : Wih0;
  const float* Whh = l ? Whh1 : Whh0;
  int n = nt*16 + (lane & 15);
  int kbase = kt*32 + (lane >> 4)*8;
  size_t base = ((((size_t)l*32 + nt)*8 + kt)*64 + lane)*8;
  for (int j = 0; j < 8; j++){
    int k = kbase + j;
    float w = (k < 128) ? Wih[n*128 + k] : Whh[n*128 + (k - 128)];
    wsw[base + j] = (short)f2bf(w);
  }
}

// W2 -> bf16, padded to 100016 rows (zeros).
__global__ __launch_bounds__(256) void prep_w2(const float* __restrict__ W2,
                                               short* __restrict__ out){
  long i = (long)blockIdx.x*256 + threadIdx.x;  // 100016*64 = 6,401,024
  if (i >= 100016L*64) return;
  long row = i >> 6;
  float v = (row < NOUT) ? W2[i] : 0.f;
  out[i] = (short)f2bf(v);
}

// ---------------------------------------------------------------------------
// Features -> x in A-fragment order, bf16 hi/lo planes.
// xfrag layout: [s(50)][bt(64)][plane(2)][kt(4)][lane(64)][8 bf16]
// Block = (bt, s): 16 batch rows x 128 features.
__global__ __launch_bounds__(256) void features(
    const int* __restrict__ pidx, const int* __restrict__ cidx,
    const float* __restrict__ age, const float* __restrict__ ts,
    const float* __restrict__ gender,
    const float* __restrict__ embp, const float* __restrict__ embc,
    const float* __restrict__ Wts, const float* __restrict__ bts,
    const float* __restrict__ Wuf, const float* __restrict__ bufv,
    short* __restrict__ xfrag){
  const int bx = blockIdx.x;
  const int bt = bx & 63, s = bx >> 6;
  const int b0 = bt*16;
  const int tid = threadIdx.x;
  __shared__ int pi[320], ci[320];
  __shared__ __align__(16) float XF[16][132];
  for (int i = tid; i < 640; i += 256){
    if (i < 320){
      int row = i/20, l = i - row*20;
      pi[i] = pidx[((size_t)(b0+row)*S_ + s)*L_ + l];
    } else {
      int j = i - 320;
      int row = j/20, l = j - row*20;
      ci[j] = cidx[((size_t)(b0+row)*S_ + s)*L_ + l];
    }
  }
  __syncthreads();
  const int m = tid >> 4, fg = tid & 15;
  float a[8];
  if (fg < 8){
    int f0 = fg*8;
    float4 s0 = {0,0,0,0}, s1 = {0,0,0,0};
    for (int l = 0; l < L_; l++){
      const float4* p = (const float4*)(embp + (size_t)pi[m*20+l]*64 + f0);
      float4 u = p[0], v = p[1];
      s0.x += u.x; s0.y += u.y; s0.z += u.z; s0.w += u.w;
      s1.x += v.x; s1.y += v.y; s1.z += v.z; s1.w += v.w;
    }
    a[0]=s0.x*0.05f; a[1]=s0.y*0.05f; a[2]=s0.z*0.05f; a[3]=s0.w*0.05f;
    a[4]=s1.x*0.05f; a[5]=s1.y*0.05f; a[6]=s1.z*0.05f; a[7]=s1.w*0.05f;
  } else if (fg < 12){
    int f0 = (fg-8)*8;
    float4 s0 = {0,0,0,0}, s1 = {0,0,0,0};
    for (int l = 0; l < L_; l++){
      const float4* p = (const float4*)(embc + (size_t)ci[m*20+l]*32 + f0);
      float4 u = p[0], v = p[1];
      s0.x += u.x; s0.y += u.y; s0.z += u.z; s0.w += u.w;
      s1.x += v.x; s1.y += v.y; s1.z += v.z; s1.w += v.w;
    }
    a[0]=s0.x*0.05f; a[1]=s0.y*0.05f; a[2]=s0.z*0.05f; a[3]=s0.w*0.05f;
    a[4]=s1.x*0.05f; a[5]=s1.y*0.05f; a[6]=s1.z*0.05f; a[7]=s1.w*0.05f;
  } else if (fg < 14){
    int j0 = (fg-12)*8;
    float tv = ts[(size_t)(b0+m)*S_ + s];
    #pragma unroll
    for (int e = 0; e < 8; e++) a[e] = tv*Wts[j0+e] + bts[j0+e];
  } else {
    int j0 = (fg-14)*8;
    float av = age[b0+m], gv = gender[b0+m];
    #pragma unroll
    for (int e = 0; e < 8; e++){
      int j = j0+e;
      a[e] = av*Wuf[2*j] + gv*Wuf[2*j+1] + bufv[j];
    }
  }
  {
    int f0 = fg*8;
    *(float4*)&XF[m][f0]   = (float4){a[0],a[1],a[2],a[3]};
    *(float4*)&XF[m][f0+4] = (float4){a[4],a[5],a[6],a[7]};
  }
  __syncthreads();
  // phase 2: emit fragment-order hi/lo planes
  const int kt = tid >> 6, ls = tid & 63;
  const int mm = ls & 15, a2 = ls >> 4;
  bh8 hv, lv;
  frag_convert_row(&XF[mm][kt*32 + a2*8], hv, lv);
  size_t ob = ((((size_t)s*64 + bt)*2 + 0)*4 + kt)*512 + (size_t)ls*8;
  *(bh8*)(xfrag + ob)        = hv;   // plane 0 (hi)
  *(bh8*)(xfrag + ob + 2048) = lv;   // plane 1 (lo)
}

// ---------------------------------------------------------------------------
// 2-layer LSTM, layer-pipelined wave teams. 64 blocks x 1024 thr (16 waves,
// 4 waves/SIMD). Waves 0-7 (team0): layer0 at step i. Waves 8-15 (team1):
// layer1 at step i-1. Team-wave u (0..7) owns output cols [u*16, u*16+16)
// (nt = g*8 + u for each gate g) -> c-state + nonlinearity register-local,
// and the C-layout output cols are exactly HALF of A-frag kt-slice (u>>1)
// -> the f32->bf16-hi/lo fragment conversion stays WAVE-INTERNAL (lanes 0-31
// emit the hi plane, lanes 32-63 the lo plane; lgkmcnt-ordered, no barrier).
// Cross-wave buffers (XA, H0, H1 frags) parity double-buffered -> ONE
// __syncthreads() per step. Per-wave work halved vs the 8-wave version so
// 4 waves/SIMD hide the L2 weight-reload latency (512KB/block/step, L1
// cannot hold it).
__global__ __launch_bounds__(1024, 4) void lstm_kernel(
    const short* __restrict__ xfrag, const short* __restrict__ wsw,
    const float* __restrict__ wsbias,
    const float* __restrict__ W1, const float* __restrict__ b1,
    short* __restrict__ hidden_bf){
  __shared__ __align__(16) short XAhi[2][2048], XAlo[2][2048]; // x(t) frags
  __shared__ __align__(16) short H0hi[2][2048], H0lo[2][2048]; // h0(t) frags
  __shared__ __align__(16) short H1hi[2][2048], H1lo[2][2048]; // h1(t) frags
  __shared__ __align__(16) float XH0f[16][132], XH1f[16][132]; // f32 C-tiles
  const int tid  = threadIdx.x;
  const int w    = tid >> 6, lane = tid & 63;
  const int col  = lane & 15, quad = lane >> 4;
  const int bt   = blockIdx.x;
  const int u    = w & 7;                 // team-wave index (0..7)
  const bool t1  = (w >= 8);              // team1 = layer 1
  const int lsel = t1 ? 1 : 0;
  const int pl2  = tid >> 9, sl2 = tid & 511;   // x-staging split over 1024 thr
  const bh8* wp = (const bh8*)wsw;

  for (int idx = tid; idx < 2048; idx += 1024){
    H0hi[1][idx] = 0; H0lo[1][idx] = 0;   // h0(-1)
    H1hi[0][idx] = 0; H1lo[0][idx] = 0;   // h1(-1)
  }
  float bz[4];
  #pragma unroll
  for (int g = 0; g < 4; g++)
    bz[g] = wsbias[lsel*512 + (g*8 + u)*16 + col];
  float cst[4] = {0,0,0,0};
  // stage x(0) into XA[0] (each thread moves 8B)
  {
    float2 v = *(const float2*)(xfrag + ((size_t)bt*2 + pl2)*2048 + (size_t)sl2*4);
    *(float2*)((pl2 ? XAlo[0] : XAhi[0]) + sl2*4) = v;
  }
  __syncthreads();

  for (int i = 0; i <= S_; i++){
    const int cb = i & 1, pb = cb ^ 1;
    // prefetch x(i+1) (latency hidden under the MFMA phase)
    int tp = (i+1 < S_) ? i+1 : S_-1;
    float2 pf = *(const float2*)(xfrag + (((size_t)tp*64 + bt)*2 + pl2)*2048 + (size_t)sl2*4);

    const bool act = t1 ? (i >= 1) : (i < S_);
    if (act){
      fx4 acc[4];
      #pragma unroll
      for (int g = 0; g < 4; g++)
        acc[g] = (fx4){bz[g], bz[g], bz[g], bz[g]};
      __builtin_amdgcn_s_setprio(1);
      #pragma unroll
      for (int kt = 0; kt < 8; kt++){
        const short* ph;
        const short* pl;
        if (!t1){ // layer0: K = [x(i) | h0(i-1)]
          ph = (kt < 4) ? &XAhi[cb][kt*512 + lane*8] : &H0hi[pb][(kt-4)*512 + lane*8];
          pl = (kt < 4) ? &XAlo[cb][kt*512 + lane*8] : &H0lo[pb][(kt-4)*512 + lane*8];
        } else {  // layer1: K = [h0(i-1) | h1(i-2)]
          ph = (kt < 4) ? &H0hi[pb][kt*512 + lane*8] : &H1hi[pb][(kt-4)*512 + lane*8];
          pl = (kt < 4) ? &H0lo[pb][kt*512 + lane*8] : &H1lo[pb][(kt-4)*512 + lane*8];
        }
        bh8 ah = *(const bh8*)ph;
        bh8 al = *(const bh8*)pl;
        #pragma unroll
        for (int g = 0; g < 4; g++){
          bh8 bb = wp[(size_t)((lsel*32 + g*8 + u)*8 + kt)*64 + lane];
          acc[g] = __builtin_amdgcn_mfma_f32_16x16x32_bf16(ah, bb, acc[g], 0, 0, 0);
          acc[g] = __builtin_amdgcn_mfma_f32_16x16x32_bf16(al, bb, acc[g], 0, 0, 0);
        }
      }
      __builtin_amdgcn_s_setprio(0);
      float (*XH)[132] = t1 ? XH1f : XH0f;
      #pragma unroll
      for (int r = 0; r < 4; r++){
        float cc = sigm(acc[1][r])*cst[r] + sigm(acc[0][r])*tanh_(acc[2][r]);
        cst[r] = cc;
        XH[quad*4 + r][u*16 + col] = sigm(acc[3][r])*tanh_(cc);
      }
      // wave-local convert: wave u transposes its own 16 cols into half of
      // A-frag slice kt4 = u>>1 (half = u&1). Lanes 0-31 write the hi plane,
      // lanes 32-63 the lo plane. Same-wave LDS dep -> lgkmcnt-ordered.
      {
        const int mm = lane & 15, qq = (lane >> 4) & 1, phase = lane >> 5;
        bh8 hv, lv;
        frag_convert_row(&XH[mm][u*16 + qq*8], hv, lv);
        const int off = (u >> 1)*512 + ((2*(u & 1) + qq)*16 + mm)*8;
        short* dsth = t1 ? &H1hi[cb][off] : &H0hi[cb][off];
        short* dstl = t1 ? &H1lo[cb][off] : &H0lo[cb][off];
        short* dst  = phase ? dstl : dsth;
        bh8   val   = phase ? lv : hv;
        *(bh8*)dst = val;
      }
    }
    // park x(i+1) into the other parity buffer (disjoint from this iter's reads)
    *(float2*)((pl2 ? XAlo[pb] : XAhi[pb]) + sl2*4) = pf;
    __syncthreads();   // publish H0[cb], H1[cb], XA[pb] for iter i+1
  }
  // XH1f holds h1(t=49) (written by team1 at iter 50, barrier'd). Fused head1.
  {
    const int mm2 = tid >> 6;          // 16 rows
    const int cc2 = tid & 63;          // 64 cols
    float s = b1[cc2];
    #pragma unroll 8
    for (int k = 0; k < 128; k++) s += XH1f[mm2][k]*W1[cc2*128 + k];
    s = fmaxf(s, 0.f);
    hidden_bf[(size_t)(bt*16 + mm2)*64 + cc2] = (short)f2bf(s);
  }
}

// ---------------------------------------------------------------------------
// logits = hidden @ W2^T + b2. Block = (chunk of 32 n-tiles) x (one m-tile);
// results re-staged through LDS so global stores are 512B-contiguous rows.
__global__ __launch_bounds__(256) void head2(
    const short* __restrict__ hid, const short* __restrict__ w2,
    const float* __restrict__ b2, float* __restrict__ out){
  __shared__ __align__(16) float HS[4][16][132];
  const int tid = threadIdx.x;
  const int w = tid >> 6, lane = tid & 63;
  const int col = lane & 15, quad = lane >> 4;
  const int mt = blockIdx.x & 63;
  const int chunk = blockIdx.x >> 6;       // 196 chunks
  const bh8* hp = (const bh8*)hid;
  bh8 a0 = hp[(size_t)(mt*16 + col)*8 + quad];
  bh8 a1 = hp[(size_t)(mt*16 + col)*8 + 4 + quad];
  const bh8* wpt = (const bh8*)w2;
  #pragma unroll
  for (int i = 0; i < 8; i++){
    int nt = chunk*32 + w*8 + i;
    if (nt < 6251){
      int n = nt*16 + col;
      bh8 b0v = wpt[(size_t)n*8 + quad];
      bh8 b1v = wpt[(size_t)n*8 + 4 + quad];
      fx4 a = {0.f,0.f,0.f,0.f};
      a = __builtin_amdgcn_mfma_f32_16x16x32_bf16(a0, b0v, a, 0, 0, 0);
      a = __builtin_amdgcn_mfma_f32_16x16x32_bf16(a1, b1v, a, 0, 0, 0);
      float bias = (n < NOUT) ? b2[n] : 0.f;
      #pragma unroll
      for (int r = 0; r < 4; r++) HS[w][quad*4 + r][i*16 + col] = a[r] + bias;
    }
  }
  __syncthreads();
  const long rowbase = (long)mt*16;
  const int n0 = chunk*512 + w*128;
  #pragma unroll
  for (int p = 0; p < 8; p++){
    int row = p*2 + (lane >> 5);
    int c4 = (lane & 31)*4;
    int gc = n0 + c4;
    float4 v = *(const float4*)&HS[w][row][c4];
    if (gc + 3 < NOUT){
      *(float4*)&out[(rowbase + row)*NOUT + gc] = v;
    } else {
      float vv[4] = {v.x, v.y, v.z, v.w};
      #pragma unroll
      for (int k2 = 0; k2 < 4; k2++)
        if (gc + k2 < NOUT) out[(rowbase + row)*NOUT + gc + k2] = vv[k2];
    }
  }
}

// ---------------------------------------------------------------------------
extern "C" void kernel_launch(void* const* d_in, const int* in_sizes, int n_in,
                              void* d_out, int out_size, void* d_ws, size_t ws_size,
                              hipStream_t stream){
  const int*   prod = (const int*)  d_in[0];
  const int*   cat  = (const int*)  d_in[1];
  const float* age  = (const float*)d_in[2];
  const float* ts   = (const float*)d_in[3];
  const float* gen  = (const float*)d_in[4];
  const float* embp = (const float*)d_in[5];
  const float* embc = (const float*)d_in[6];
  const float* Wts  = (const float*)d_in[7];
  const float* bts  = (const float*)d_in[8];
  const float* Wuf  = (const float*)d_in[9];
  const float* bufv = (const float*)d_in[10];
  const float* Wih0 = (const float*)d_in[11];
  const float* Whh0 = (const float*)d_in[12];
  const float* bih0 = (const float*)d_in[13];
  const float* bhh0 = (const float*)d_in[14];
  const float* Wih1 = (const float*)d_in[15];
  const float* Whh1 = (const float*)d_in[16];
  const float* bih1 = (const float*)d_in[17];
  const float* bhh1 = (const float*)d_in[18];
  const float* W1   = (const float*)d_in[19];
  const float* b1   = (const float*)d_in[20];
  const float* W2   = (const float*)d_in[21];
  const float* b2   = (const float*)d_in[22];
  float* out = (float*)d_out;

  char* ws = (char*)d_ws;
  short* ws_x    = (short*)(ws);               // xfrag: 26,214,400 B
  short* ws_w    = (short*)(ws + 26214400);    // lstm W frags: 524,288 B
  float* ws_bias = (float*)(ws + 26738688);    // [2][512] f32: 4,096 B
  short* ws_hid  = (short*)(ws + 26742784);    // hidden bf16 [1024][64]: 131,072 B
  short* ws_w2   = (short*)(ws + 26873856);    // W2 bf16 [100016][64]: 12,802,048 B

  prep_lstm_w<<<128, 256, 0, stream>>>(Wih0, Whh0, bih0, bhh0,
                                       Wih1, Whh1, bih1, bhh1, ws_w, ws_bias);
  prep_w2<<<25004, 256, 0, stream>>>(W2, ws_w2);
  features<<<3200, 256, 0, stream>>>(prod, cat, age, ts, gen, embp, embc,
                                     Wts, bts, Wuf, bufv, ws_x);
  lstm_kernel<<<64, 1024, 0, stream>>>(ws_x, ws_w, ws_bias, W1, b1, ws_hid);
  head2<<<196*64, 256, 0, stream>>>(ws_hid, ws_w2, b2, out);
}